// Round 7
// baseline (186.033 us; speedup 1.0000x reference)
//
#include <hip/hip_runtime.h>

typedef unsigned short u16;
typedef _Float16 f16x2 __attribute__((ext_vector_type(2)));
typedef _Float16 f16x8 __attribute__((ext_vector_type(8)));
typedef float    f32x4  __attribute__((ext_vector_type(4)));
typedef float    f32x16 __attribute__((ext_vector_type(16)));

// Fragment k-map convention (same in BOTH operand slots — proven r1-r6):
//   k_local(lane, j) = (lane>>5)*4 + (j&3) + 8*(j>>2),  j = 0..7
// D layout (m74/m101): col = lane&31 (N), row = (r&3)+8*(r>>2)+4*(lane>>5) (M)

union U4 { uint4 u; f16x8 h; u16 s[8]; };
union HU { f16x2 h2[4]; f16x8 h8; };

// ---------------------------------------------------------------------------
// Prep: ws layout (bytes):
//   [0,139264)        Bf = W2flat in B-fragment order, 136 ksteps
//                     (0..127 = W2, 128..129 = b2 rows, 130..135 zero — unused)
//   [139264,141312)   W1f normal   (col = nt*32 + l31)
//   [141312,143360)   W1fs swapped (col = nt*32 + (l31^4)) -> D rows m^4
//   [143360,143616)   b1p[h'][nt][r] = b1[nt*32 + (r&3)+8*(r>>2)+4h']  (f32)
// ---------------------------------------------------------------------------
__global__ void prep_kernel(const float* __restrict__ W1,
                            const float* __restrict__ b1,
                            const float* __restrict__ W2,
                            const float* __restrict__ b2,
                            u16* __restrict__ ws)
{
    int id = blockIdx.x * 256 + threadIdx.x;
    if (id < 8704) {                       // 136 ksteps * 64 lanes
        int k2 = id >> 6, l = id & 63;
        int h = l >> 5, col = l & 31;
        U4 o;
        if (k2 < 130) {
            #pragma unroll
            for (int g = 0; g < 2; ++g) {
                int base4 = k2 * 16 + g * 8 + h * 4;   // 4-aligned
                f32x4 v;
                if (base4 < 2048) {
                    int k1 = base4 >> 5, j32 = base4 & 31;
                    v = *(const f32x4*)&W2[k1 * 1024 + col * 32 + j32];
                } else {
                    v = *(const f32x4*)&b2[col * 32 + (base4 - 2048)];
                }
                #pragma unroll
                for (int j = 0; j < 4; ++j)
                    o.h[g * 4 + j] = (_Float16)v[j];
            }
        } else {
            o.u = uint4{0u, 0u, 0u, 0u};
        }
        *(uint4*)(ws + id * 8) = o.u;
    } else if (id < 8960) {                // W1f (128) + W1fs (128)
        int idx = id - 8704;
        int sw  = idx >> 7;                // 0 = normal, 1 = swapped
        int nt = (idx >> 6) & 1, l = idx & 63;
        int h = l >> 5;
        int c31 = sw ? ((l & 31) ^ 4) : (l & 31);
        int col = nt * 32 + c31;
        U4 o;
        #pragma unroll
        for (int g = 0; g < 2; ++g)
            #pragma unroll
            for (int j = 0; j < 4; ++j) {
                int k = g * 8 + h * 4 + j;
                o.h[g * 4 + j] = (_Float16)W1[k * 64 + col];
            }
        *(uint4*)(ws + 69632 + idx * 8) = o.u;
    } else if (id < 9024) {                // b1p: 2h' * 2nt * 16r floats
        int idx = id - 8960;
        int hh = idx >> 5, nt = (idx >> 4) & 1, r = idx & 15;
        int row = (r & 3) + 8 * (r >> 2) + 4 * hh;
        ((float*)(ws + 71680))[idx] = b1[nt * 32 + row];
    }
}

__device__ __forceinline__ void stage16(const void* g, void* l) {
    __builtin_amdgcn_global_load_lds(
        (const __attribute__((address_space(1))) void*)g,
        (__attribute__((address_space(3))) void*)l, 16, 0, 0);
}

// ---------------------------------------------------------------------------
// Main kernel: PERSISTENT. grid = 256 blocks x 512 threads; 130 KB LDS forces
// 1 block/CU. Stage ALL of B into LDS once, ONE __syncthreads, then each of
// the 8 waves independently grid-strides over 64-edge tiles (mt=2, proven
// 84-VGPR spill-free config) with ZERO barriers in the main loop — LDS reads
// / VALU / MFMA of different waves free-run and overlap. Inner K loop fully
// unrolled, 2-deep rotating LDS prefetch (issue-to-use ~2 ksteps).
// hdn in registers via the dual-W1 transposed layer-1 (validated r5/r6).
// ---------------------------------------------------------------------------
#define LDB(k1, hf) (*(const uint4*)(shb + (k1) * 2048 + (hf) * 1024 + lane * 16))

__global__ __launch_bounds__(512, 2) void edge_kernel(
    const float* __restrict__ h_w,
    const float* __restrict__ ef,
    const u16*  __restrict__ ws,
    float* __restrict__ out,
    int E)
{
    __shared__ alignas(16) char shb[133120];   // 130 KB: all 130 B-ksteps
    const int tid  = threadIdx.x;
    const int lane = tid & 63;
    const int l31  = lane & 31;
    const int h    = lane >> 5;
    const int wv   = tid >> 6;
    const char* wsb = (const char*)ws;

    // ---- stage the whole B panel (17 rounds of 512 x 16 B) ----
    #pragma unroll
    for (int r = 0; r < 16; ++r)
        stage16(wsb + r * 8192 + tid * 16, shb + r * 8192 + tid * 16);
    if (tid < 128)
        stage16(wsb + 131072 + tid * 16, shb + 131072 + tid * 16);

    // ---- persistent W1 fragments + permuted bias (registers) ----
    const uint4* W1f  = (const uint4*)(ws + 69632);
    const uint4* W1fs = (const uint4*)(ws + 70656);
    U4 wn0, wn1, wsw0, wsw1;
    wn0.u  = W1f[lane];   wn1.u  = W1f[64 + lane];
    wsw0.u = W1fs[lane];  wsw1.u = W1fs[64 + lane];
    const float* b1pf = (const float*)(ws + 71680);
    f32x4 bvo[2][4], bvf[2][4];
    #pragma unroll
    for (int nt = 0; nt < 2; ++nt)
        #pragma unroll
        for (int qr = 0; qr < 4; ++qr) {
            bvo[nt][qr] = *(const f32x4*)(b1pf + h * 32 + nt * 16 + qr * 4);
            bvf[nt][qr] = *(const f32x4*)(b1pf + (1 - h) * 32 + nt * 16 + qr * 4);
        }

    asm volatile("s_waitcnt vmcnt(0)" ::: "memory");
    __syncthreads();   // the ONLY barrier

    // ---- per-wave independent loop over 64-edge tiles ----
    for (int base = (blockIdx.x * 8 + wv) * 64; base < E; base += 256 * 512) {

        // h_w fragments
        f16x2 hwA[2][2][4];
        #pragma unroll
        for (int mt = 0; mt < 2; ++mt) {
            int e = base + mt * 32 + l31;
            bool ok = e < E;
            f32x4 q0 = {}, q1 = {}, q2 = {}, q3 = {};
            if (ok) {
                const float* hp = h_w + (size_t)e * 32 + h * 4;
                q0 = *(const f32x4*)(hp);
                q1 = *(const f32x4*)(hp + 8);
                q2 = *(const f32x4*)(hp + 16);
                q3 = *(const f32x4*)(hp + 24);
            }
            hwA[mt][0][0] = f16x2{ (_Float16)q0[0], (_Float16)q0[1] };
            hwA[mt][0][1] = f16x2{ (_Float16)q0[2], (_Float16)q0[3] };
            hwA[mt][0][2] = f16x2{ (_Float16)q1[0], (_Float16)q1[1] };
            hwA[mt][0][3] = f16x2{ (_Float16)q1[2], (_Float16)q1[3] };
            hwA[mt][1][0] = f16x2{ (_Float16)q2[0], (_Float16)q2[1] };
            hwA[mt][1][1] = f16x2{ (_Float16)q2[2], (_Float16)q2[3] };
            hwA[mt][1][2] = f16x2{ (_Float16)q3[0], (_Float16)q3[1] };
            hwA[mt][1][3] = f16x2{ (_Float16)q3[2], (_Float16)q3[3] };
        }

        // layer 1 (transposed, dual-W1) -> Q registers
        f16x2 QA[2][2][8], QB[2][2][8];
        #pragma unroll
        for (int mt = 0; mt < 2; ++mt) {
            int e = base + mt * 32 + l31;
            bool ok = e < E;
            f32x4 g0 = {}, g1 = {};
            if (ok) {
                g0 = *(const f32x4*)&ef[e * 16 + h * 4];
                g1 = *(const f32x4*)&ef[e * 16 + 8 + h * 4];
            }
            U4 a;
            #pragma unroll
            for (int j = 0; j < 4; ++j) {
                a.h[j]     = (_Float16)g0[j];
                a.h[4 + j] = (_Float16)g1[j];
            }
            f32x16 cn0 = {}, cn1 = {}, cs0 = {}, cs1 = {};
            cn0 = __builtin_amdgcn_mfma_f32_32x32x16_f16(wn0.h,  a.h, cn0, 0, 0, 0);
            cn1 = __builtin_amdgcn_mfma_f32_32x32x16_f16(wn1.h,  a.h, cn1, 0, 0, 0);
            cs0 = __builtin_amdgcn_mfma_f32_32x32x16_f16(wsw0.h, a.h, cs0, 0, 0, 0);
            cs1 = __builtin_amdgcn_mfma_f32_32x32x16_f16(wsw1.h, a.h, cs1, 0, 0, 0);
            #pragma unroll
            for (int nt = 0; nt < 2; ++nt) {
                #pragma unroll
                for (int p = 0; p < 8; ++p) {
                    const int r0 = 2 * p, r1 = 2 * p + 1;
                    float n0 = fmaxf((nt ? cn1[r0] : cn0[r0]) + bvo[nt][r0 >> 2][r0 & 3], 0.f);
                    float n1 = fmaxf((nt ? cn1[r1] : cn0[r1]) + bvo[nt][r1 >> 2][r1 & 3], 0.f);
                    float s0 = fmaxf((nt ? cs1[r0] : cs0[r0]) + bvf[nt][r0 >> 2][r0 & 3], 0.f);
                    float s1 = fmaxf((nt ? cs1[r1] : cs0[r1]) + bvf[nt][r1 >> 2][r1 & 3], 0.f);
                    f16x2 pn = { (_Float16)n0, (_Float16)n1 };
                    f16x2 ps = { (_Float16)s0, (_Float16)s1 };
                    QA[mt][nt][p] = h ? ps : pn;
                    QB[mt][nt][p] = h ? pn : ps;
                }
            }
        }

        f32x16 acc0 = {}, acc1 = {};

        // K loop: fully unrolled, 2-deep rotating LDS prefetch, no barriers
        U4 pA[2], pB[2];
        pA[0].u = LDB(0, 0); pB[0].u = LDB(0, 1);
        pA[1].u = LDB(1, 0); pB[1].u = LDB(1, 1);
        #pragma unroll
        for (int k1 = 0; k1 < 64; ++k1) {
            const int s = k1 & 1;
            U4 b0 = pA[s], b1f = pB[s];
            pA[s].u = LDB(k1 + 2, 0);      // k1+2 <= 65 <= 129: always valid
            pB[s].u = LDB(k1 + 2, 1);
            const int nt   = k1 >> 5;
            const int kk   = k1 & 31;
            const int hq   = (kk >> 2) & 1;
            const int p    = ((kk >> 3) << 1) + ((kk & 3) >> 1);
            const int half = kk & 1;
            {
                _Float16 x = hq ? QB[0][nt][p][half] : QA[0][nt][p][half];
                f16x2 hh = { x, x };
                HU A;
                #pragma unroll
                for (int rr = 0; rr < 4; ++rr) A.h2[rr] = hh * hwA[0][0][rr];
                acc0 = __builtin_amdgcn_mfma_f32_32x32x16_f16(A.h8, b0.h, acc0, 0, 0, 0);
                #pragma unroll
                for (int rr = 0; rr < 4; ++rr) A.h2[rr] = hh * hwA[0][1][rr];
                acc0 = __builtin_amdgcn_mfma_f32_32x32x16_f16(A.h8, b1f.h, acc0, 0, 0, 0);
            }
            {
                _Float16 x = hq ? QB[1][nt][p][half] : QA[1][nt][p][half];
                f16x2 hh = { x, x };
                HU A;
                #pragma unroll
                for (int rr = 0; rr < 4; ++rr) A.h2[rr] = hh * hwA[1][0][rr];
                acc1 = __builtin_amdgcn_mfma_f32_32x32x16_f16(A.h8, b0.h, acc1, 0, 0, 0);
                #pragma unroll
                for (int rr = 0; rr < 4; ++rr) A.h2[rr] = hh * hwA[1][1][rr];
                acc1 = __builtin_amdgcn_mfma_f32_32x32x16_f16(A.h8, b1f.h, acc1, 0, 0, 0);
            }
        }
        // k1 = 64: bias row (hdn == 1) -> A = hwA directly; data in pA[0]/pB[0]
        {
            U4 b0 = pA[0], b1f = pB[0];
            HU A0, A1;
            #pragma unroll
            for (int rr = 0; rr < 4; ++rr) { A0.h2[rr] = hwA[0][0][rr]; A1.h2[rr] = hwA[1][0][rr]; }
            acc0 = __builtin_amdgcn_mfma_f32_32x32x16_f16(A0.h8, b0.h, acc0, 0, 0, 0);
            acc1 = __builtin_amdgcn_mfma_f32_32x32x16_f16(A1.h8, b0.h, acc1, 0, 0, 0);
            #pragma unroll
            for (int rr = 0; rr < 4; ++rr) { A0.h2[rr] = hwA[0][1][rr]; A1.h2[rr] = hwA[1][1][rr]; }
            acc0 = __builtin_amdgcn_mfma_f32_32x32x16_f16(A0.h8, b1f.h, acc0, 0, 0, 0);
            acc1 = __builtin_amdgcn_mfma_f32_32x32x16_f16(A1.h8, b1f.h, acc1, 0, 0, 0);
        }

        // store
        #pragma unroll
        for (int mt = 0; mt < 2; ++mt) {
            #pragma unroll
            for (int r = 0; r < 16; ++r) {
                int row = (r & 3) + 8 * (r >> 2) + 4 * h;
                int e = base + mt * 32 + row;
                float v = (mt == 0) ? acc0[r] : acc1[r];
                if (e < E) out[(size_t)e * 32 + l31] = v;
            }
        }
    }
}

extern "C" void kernel_launch(void* const* d_in, const int* in_sizes, int n_in,
                              void* d_out, int out_size, void* d_ws, size_t ws_size,
                              hipStream_t stream)
{
    // inputs: 0=h_v (unused), 1=h_w, 2=edge_features, 3=W1, 4=b1, 5=W2, 6=b2
    const float* h_w = (const float*)d_in[1];
    const float* ef  = (const float*)d_in[2];
    const float* W1  = (const float*)d_in[3];
    const float* b1  = (const float*)d_in[4];
    const float* W2  = (const float*)d_in[5];
    const float* b2  = (const float*)d_in[6];
    float* out = (float*)d_out;
    const int E = in_sizes[1] / 32;
    u16* ws = (u16*)d_ws;   // needs 143,616 B

    prep_kernel<<<36, 256, 0, stream>>>(W1, b1, W2, b2, ws);

    edge_kernel<<<256, 512, 0, stream>>>(h_w, ef, ws, out, E);
}

// Round 8
// 47.808 us; speedup vs baseline: 3.8912x; 3.8912x over previous
//
#include <hip/hip_runtime.h>

typedef unsigned short u16;
typedef _Float16 f16x2 __attribute__((ext_vector_type(2)));
typedef _Float16 f16x8 __attribute__((ext_vector_type(8)));
typedef float    f32x4  __attribute__((ext_vector_type(4)));
typedef float    f32x16 __attribute__((ext_vector_type(16)));

// Fragment k-map convention (same in BOTH operand slots — proven r1-r7):
//   k_local(lane, j) = (lane>>5)*4 + (j&3) + 8*(j>>2),  j = 0..7
// D layout (m74/m101): col = lane&31 (N), row = (r&3)+8*(r>>2)+4*(lane>>5) (M)

union U4 { uint4 u; f16x8 h; u16 s[8]; };
union HU { f16x2 h2[4]; f16x8 h8; };

// ---------------------------------------------------------------------------
// Prep: Bf = W2flat (2080 x 32, f16) in MFMA B-fragment order [0,133120);
// W1f fragments [133120,135168); b1p permuted bias table f32 [135168,135424):
//   b1p[h][nt][r] = b1[nt*32 + (r&3)+8*(r>>2)+4h]
// ---------------------------------------------------------------------------
__global__ void prep_kernel(const float* __restrict__ W1,
                            const float* __restrict__ b1,
                            const float* __restrict__ W2,
                            const float* __restrict__ b2,
                            u16* __restrict__ ws)
{
    int id = blockIdx.x * 256 + threadIdx.x;
    if (id < 8320) {                       // 130 ksteps * 64 lanes
        int k2 = id >> 6, l = id & 63;
        int h = l >> 5, col = l & 31;
        U4 o;
        #pragma unroll
        for (int g = 0; g < 2; ++g) {
            int base4 = k2 * 16 + g * 8 + h * 4;   // 4-aligned, no 32-straddle
            f32x4 v;
            if (base4 < 2048) {
                int k1 = base4 >> 5, j32 = base4 & 31;
                v = *(const f32x4*)&W2[k1 * 1024 + col * 32 + j32];
            } else {
                v = *(const f32x4*)&b2[col * 32 + (base4 - 2048)];
            }
            #pragma unroll
            for (int j = 0; j < 4; ++j)
                o.h[g * 4 + j] = (_Float16)v[j];
        }
        *(uint4*)(ws + id * 8) = o.u;
    } else if (id < 8448) {                // W1 fragments: 2 ntiles * 64 lanes
        int idx = id - 8320;
        int nt = idx >> 6, l = idx & 63;
        int h = l >> 5, col = nt * 32 + (l & 31);
        U4 o;
        #pragma unroll
        for (int g = 0; g < 2; ++g)
            #pragma unroll
            for (int j = 0; j < 4; ++j) {
                int k = g * 8 + h * 4 + j;
                o.h[g * 4 + j] = (_Float16)W1[k * 64 + col];
            }
        *(uint4*)(ws + id * 8) = o.u;
    } else if (id < 8512) {                // b1p: 2h * 2nt * 16r floats
        int idx = id - 8448;
        int hh = idx >> 5, nt = (idx >> 4) & 1, r = idx & 15;
        int row = (r & 3) + 8 * (r >> 2) + 4 * hh;
        ((float*)(ws + 67584))[idx] = b1[nt * 32 + row];
    }
}

__device__ __forceinline__ void stage16(const void* g, void* l) {
    __builtin_amdgcn_global_load_lds(
        (const __attribute__((address_space(1))) void*)g,
        (__attribute__((address_space(3))) void*)l, 16, 0, 0);
}

// ---------------------------------------------------------------------------
// Main kernel: r4 structure EXACTLY (4 waves/block, 64 edges/wave, 32 KB LDS
// B double-buffer, transposed-layer-1 Q-in-regs, 8 chunk barriers) with ONE
// change: each accumulator is split into even/odd-k1 chains -> 4 independent
// MFMA dependency chains per wave (was 2). A 32x32 MFMA's result->use
// latency (~4-pass pipe) left 2 chains unable to keep the matrix pipe fed;
// 4 chains halve the per-chain issue-rate requirement. +32 VGPR, summed in
// the epilogue.
// ---------------------------------------------------------------------------
__global__ __launch_bounds__(256, 3) void edge_kernel(
    const float* __restrict__ h_w,
    const float* __restrict__ ef,
    const u16*  __restrict__ ws,
    float* __restrict__ out,
    int E)
{
    __shared__ alignas(16) u16 shm[16384];   // 32 KB
    const int tid  = threadIdx.x;
    const int lane = tid & 63;
    const int l31  = lane & 31;
    const int h    = lane >> 5;
    const int tileBase = (blockIdx.x * 4 + (tid >> 6)) * 64;
    const char* wsb = (const char*)ws;
    char*       shb = (char*)shm;

    // ---- stage chunk 0 (16 KB = k1 0..7) ----
    #pragma unroll
    for (int j = 0; j < 4; ++j)
        stage16(wsb + j * 4096 + tid * 16, shb + j * 4096 + tid * 16);

    // ---- h_w fragments (issued early; f16, kept in regs) ----
    f16x2 hwA[2][2][4];
    #pragma unroll
    for (int mt = 0; mt < 2; ++mt) {
        int e = tileBase + mt * 32 + l31;
        bool ok = e < E;
        f32x4 q0 = {}, q1 = {}, q2 = {}, q3 = {};
        if (ok) {
            const float* hp = h_w + (size_t)e * 32 + h * 4;
            q0 = *(const f32x4*)(hp);
            q1 = *(const f32x4*)(hp + 8);
            q2 = *(const f32x4*)(hp + 16);
            q3 = *(const f32x4*)(hp + 24);
        }
        hwA[mt][0][0] = f16x2{ (_Float16)q0[0], (_Float16)q0[1] };
        hwA[mt][0][1] = f16x2{ (_Float16)q0[2], (_Float16)q0[3] };
        hwA[mt][0][2] = f16x2{ (_Float16)q1[0], (_Float16)q1[1] };
        hwA[mt][0][3] = f16x2{ (_Float16)q1[2], (_Float16)q1[3] };
        hwA[mt][1][0] = f16x2{ (_Float16)q2[0], (_Float16)q2[1] };
        hwA[mt][1][1] = f16x2{ (_Float16)q2[2], (_Float16)q2[3] };
        hwA[mt][1][2] = f16x2{ (_Float16)q3[0], (_Float16)q3[1] };
        hwA[mt][1][3] = f16x2{ (_Float16)q3[2], (_Float16)q3[3] };
    }

    // ---- layer 1 (transposed): c = mfma(W1f as A, ef as B) ----
    const uint4* W1f = (const uint4*)(ws + 8320 * 8);
    U4 w1f0, w1f1;
    w1f0.u = W1f[lane];
    w1f1.u = W1f[64 + lane];
    const float* b1pf = (const float*)(ws + 67584);
    f32x4 bv[2][4];
    #pragma unroll
    for (int nt = 0; nt < 2; ++nt)
        #pragma unroll
        for (int qr = 0; qr < 4; ++qr)
            bv[nt][qr] = *(const f32x4*)(b1pf + h * 32 + nt * 16 + qr * 4);

    f16x2 Q[2][2][8][2];   // [mt][nt][p][hq]  — all indices compile-time
    #pragma unroll
    for (int mt = 0; mt < 2; ++mt) {
        int e = tileBase + mt * 32 + l31;
        bool ok = e < E;
        f32x4 g0 = {}, g1 = {};
        if (ok) {
            g0 = *(const f32x4*)&ef[e * 16 + h * 4];
            g1 = *(const f32x4*)&ef[e * 16 + 8 + h * 4];
        }
        U4 a;
        #pragma unroll
        for (int j = 0; j < 4; ++j) {
            a.h[j]     = (_Float16)g0[j];
            a.h[4 + j] = (_Float16)g1[j];
        }
        f32x16 c0 = {}, c1 = {};
        c0 = __builtin_amdgcn_mfma_f32_32x32x16_f16(w1f0.h, a.h, c0, 0, 0, 0);
        c1 = __builtin_amdgcn_mfma_f32_32x32x16_f16(w1f1.h, a.h, c1, 0, 0, 0);
        #pragma unroll
        for (int nt = 0; nt < 2; ++nt) {
            #pragma unroll
            for (int p = 0; p < 8; ++p) {
                float r0 = (nt ? c1[2 * p]     : c0[2 * p]);
                float r1 = (nt ? c1[2 * p + 1] : c0[2 * p + 1]);
                float v0 = fmaxf(r0 + bv[nt][p >> 1][(2 * p) & 3],     0.f);
                float v1 = fmaxf(r1 + bv[nt][p >> 1][(2 * p + 1) & 3], 0.f);
                f16x2 own = { (_Float16)v0, (_Float16)v1 };
                unsigned swu = __shfl_xor(__builtin_bit_cast(unsigned, own), 32, 64);
                f16x2 sw = __builtin_bit_cast(f16x2, swu);
                Q[mt][nt][p][0] = h ? sw : own;   // hq = 0 version
                Q[mt][nt][p][1] = h ? own : sw;   // hq = 1 version
            }
        }
    }

    // 4 independent accumulator chains: [mt][parity of k1]
    f32x16 accA[2] = {}, accB[2] = {};
    __syncthreads();   // chunk-0 stage drained

    // ---- K loop: 8 chunks x 8 k1, fully unrolled (static Q indexing) ----
    #pragma unroll
    for (int c = 0; c < 8; ++c) {
        if (c < 7) {                       // stage chunk c+1 (16 KB)
            #pragma unroll
            for (int j = 0; j < 4; ++j)
                stage16(wsb + (c + 1) * 16384 + j * 4096 + tid * 16,
                        shb + ((c + 1) & 1) * 16384 + j * 4096 + tid * 16);
        } else {                           // stage tail (2 KB, ksteps 128-129) into buf0
            if (tid < 128)
                stage16(wsb + 131072 + tid * 16, shb + tid * 16);
        }
        const char* bB = shb + (c & 1) * 16384;
        #pragma unroll
        for (int qq = 0; qq < 8; ++qq) {
            const int k1   = c * 8 + qq;
            const int nt   = k1 >> 5;
            const int q    = k1 & 31;
            const int pa   = ((q & 3) >> 1) + 2 * (q >> 3);
            const int half = q & 1;
            const int hq   = (q >> 2) & 1;
            U4 bf0, bf1;
            bf0.u = *(const uint4*)(bB + (2 * qq) * 1024 + lane * 16);
            bf1.u = *(const uint4*)(bB + (2 * qq + 1) * 1024 + lane * 16);
            _Float16 x0 = Q[0][nt][pa][hq][half];
            _Float16 x1 = Q[1][nt][pa][hq][half];
            f16x2 hh0 = { x0, x0 }, hh1 = { x1, x1 };
            HU A0, A1;
            #pragma unroll
            for (int rr = 0; rr < 4; ++rr) { A0.h2[rr] = hh0 * hwA[0][0][rr]; A1.h2[rr] = hh1 * hwA[1][0][rr]; }
            if (qq & 1) {
                accB[0] = __builtin_amdgcn_mfma_f32_32x32x16_f16(A0.h8, bf0.h, accB[0], 0, 0, 0);
                accB[1] = __builtin_amdgcn_mfma_f32_32x32x16_f16(A1.h8, bf0.h, accB[1], 0, 0, 0);
            } else {
                accA[0] = __builtin_amdgcn_mfma_f32_32x32x16_f16(A0.h8, bf0.h, accA[0], 0, 0, 0);
                accA[1] = __builtin_amdgcn_mfma_f32_32x32x16_f16(A1.h8, bf0.h, accA[1], 0, 0, 0);
            }
            #pragma unroll
            for (int rr = 0; rr < 4; ++rr) { A0.h2[rr] = hh0 * hwA[0][1][rr]; A1.h2[rr] = hh1 * hwA[1][1][rr]; }
            if (qq & 1) {
                accB[0] = __builtin_amdgcn_mfma_f32_32x32x16_f16(A0.h8, bf1.h, accB[0], 0, 0, 0);
                accB[1] = __builtin_amdgcn_mfma_f32_32x32x16_f16(A1.h8, bf1.h, accB[1], 0, 0, 0);
            } else {
                accA[0] = __builtin_amdgcn_mfma_f32_32x32x16_f16(A0.h8, bf1.h, accA[0], 0, 0, 0);
                accA[1] = __builtin_amdgcn_mfma_f32_32x32x16_f16(A1.h8, bf1.h, accA[1], 0, 0, 0);
            }
        }
        __syncthreads();
    }

    // ---- tail k1 = 64 (hdn == 1): A-frag = hwA directly, B in buf0 ----
    {
        U4 bf0, bf1;
        bf0.u = *(const uint4*)(shb + lane * 16);
        bf1.u = *(const uint4*)(shb + 1024 + lane * 16);
        HU A0, A1;
        #pragma unroll
        for (int rr = 0; rr < 4; ++rr) { A0.h2[rr] = hwA[0][0][rr]; A1.h2[rr] = hwA[1][0][rr]; }
        accA[0] = __builtin_amdgcn_mfma_f32_32x32x16_f16(A0.h8, bf0.h, accA[0], 0, 0, 0);
        accA[1] = __builtin_amdgcn_mfma_f32_32x32x16_f16(A1.h8, bf0.h, accA[1], 0, 0, 0);
        #pragma unroll
        for (int rr = 0; rr < 4; ++rr) { A0.h2[rr] = hwA[0][1][rr]; A1.h2[rr] = hwA[1][1][rr]; }
        accA[0] = __builtin_amdgcn_mfma_f32_32x32x16_f16(A0.h8, bf1.h, accA[0], 0, 0, 0);
        accA[1] = __builtin_amdgcn_mfma_f32_32x32x16_f16(A1.h8, bf1.h, accA[1], 0, 0, 0);
    }

    // ---- store messages (sum the two chains) ----
    #pragma unroll
    for (int mt = 0; mt < 2; ++mt) {
        #pragma unroll
        for (int r = 0; r < 16; ++r) {
            int row = (r & 3) + 8 * (r >> 2) + 4 * h;
            int e = tileBase + mt * 32 + row;
            if (e < E) out[(size_t)e * 32 + l31] = accA[mt][r] + accB[mt][r];
        }
    }
}

extern "C" void kernel_launch(void* const* d_in, const int* in_sizes, int n_in,
                              void* d_out, int out_size, void* d_ws, size_t ws_size,
                              hipStream_t stream)
{
    // inputs: 0=h_v (unused), 1=h_w, 2=edge_features, 3=W1, 4=b1, 5=W2, 6=b2
    const float* h_w = (const float*)d_in[1];
    const float* ef  = (const float*)d_in[2];
    const float* W1  = (const float*)d_in[3];
    const float* b1  = (const float*)d_in[4];
    const float* W2  = (const float*)d_in[5];
    const float* b2  = (const float*)d_in[6];
    float* out = (float*)d_out;
    const int E = in_sizes[1] / 32;
    u16* ws = (u16*)d_ws;   // needs 135,424 B

    prep_kernel<<<34, 256, 0, stream>>>(W1, b1, W2, b2, ws);

    const int blocks = (E + 255) / 256;
    edge_kernel<<<blocks, 256, 0, stream>>>(h_w, ef, ws, out, E);
}